// Round 3
// baseline (455.179 us; speedup 1.0000x reference)
//
#include <hip/hip_runtime.h>

typedef __attribute__((ext_vector_type(8))) short bf16x8;
typedef __attribute__((ext_vector_type(4))) short bf16x4;
typedef __attribute__((ext_vector_type(4))) float f32x4;

#define BATCH 2
#define CH    512
#define NPIX  4096
#define NSP   4
#define SPK   1024   // keys per split
#define KT    32     // keys per tile

__device__ __forceinline__ unsigned short f2b(float f) {
    unsigned int u; __builtin_memcpy(&u, &f, 4);
    u = u + 0x7FFFu + ((u >> 16) & 1u);   // RNE
    return (unsigned short)(u >> 16);
}
__device__ __forceinline__ float b2f(unsigned short h) {
    unsigned int u = ((unsigned int)h) << 16;
    float f; __builtin_memcpy(&f, &u, 4);
    return f;
}
// async 16B/lane global->LDS (wave-uniform LDS base, per-lane global src)
__device__ __forceinline__ void gll16(void* lds, const void* g) {
    __builtin_amdgcn_global_load_lds(
        (const __attribute__((address_space(1))) void*)g,
        (__attribute__((address_space(3))) void*)lds, 16, 0, 0);
}

// ---------------------------------------------------------------- fp32 -> bf16 weight convert
__global__ __launch_bounds__(256) void convert_kernel(
    const float* __restrict__ qkv_w, const float* __restrict__ proj_w,
    unsigned short* __restrict__ wbf)
{
    int i = blockIdx.x * 256 + threadIdx.x;            // grid covers 1048576
    float v = (i < 786432) ? qkv_w[i] : proj_w[i - 786432];
    wbf[i] = f2b(v);
}

// ---------------------------------------------------------------- GN stats
__global__ __launch_bounds__(256) void stats_kernel(
    const float* __restrict__ x, float* __restrict__ stats)
{
    int bg = blockIdx.x;           // 64 blocks: b*32+g
    int b = bg >> 5, g = bg & 31;
    const float* xp = x + ((size_t)b * CH + (size_t)g * 16) * NPIX;
    float s = 0.f, ss = 0.f;
    for (int i = threadIdx.x; i < 16 * NPIX; i += 256) {
        float v = xp[i]; s += v; ss += v * v;
    }
    for (int off = 32; off; off >>= 1) {
        s  += __shfl_down(s,  off, 64);
        ss += __shfl_down(ss, off, 64);
    }
    __shared__ float red[2][4];
    int wv = threadIdx.x >> 6;
    if ((threadIdx.x & 63) == 0) { red[0][wv] = s; red[1][wv] = ss; }
    __syncthreads();
    if (threadIdx.x == 0) {
        s  = red[0][0] + red[0][1] + red[0][2] + red[0][3];
        ss = red[1][0] + red[1][1] + red[1][2] + red[1][3];
        const float inv = 1.f / (16 * NPIX);
        float mean = s * inv;
        float var  = ss * inv - mean * mean;
        stats[bg * 2 + 0] = mean;
        stats[bg * 2 + 1] = rsqrtf(var + 1e-6f);
    }
}

// ---------------------------------------------------------------- Q/K/V GEMM
// grid (128 pixtiles, 2 batch, 3 thirds) = 768 blocks = 3/CU (12 waves/CU).
// third 0 -> Q (pre-scaled, [b][n][c]); 1 -> K ([b][n][c]); 2 -> V ([b][c][n]).
__global__ __launch_bounds__(256, 3) void qkv_kernel(
    const float* __restrict__ x,
    const unsigned short* __restrict__ wbf,  // bf16 qkv_w [1536][512]
    const float* __restrict__ bias,
    const float* __restrict__ gamma,
    const float* __restrict__ beta,
    const float* __restrict__ stats,
    unsigned short* __restrict__ Q,
    unsigned short* __restrict__ K,
    unsigned short* __restrict__ V)
{
    __shared__ unsigned short hn[32][520];
    int b     = blockIdx.y;
    int third = blockIdx.z;
    int m0    = blockIdx.x * 32;
    int tid = threadIdx.x;
    {   // stage hn: p = tid&31 (pixel), cg = tid>>5 (channel slot, 8 wide)
        const float* xb = x + (size_t)b * CH * NPIX;
        const float* st = stats + b * 64;
        int p = tid & 31, cg = tid >> 5;
        for (int c0 = 0; c0 < CH; c0 += 8) {
            int c = c0 + cg;
            float mean = st[(c >> 4) * 2 + 0];
            float rstd = st[(c >> 4) * 2 + 1];
            float ga = gamma[c] * rstd;
            float be = beta[c] - mean * ga;
            hn[p][c] = f2b(xb[(size_t)c * NPIX + m0 + p] * ga + be);
        }
    }
    __syncthreads();

    int wv = tid >> 6, lane = tid & 63, ln = lane & 15, quad = lane >> 4;
    const float scale = 0.04419417382415922f;  // 512^-0.5
    #pragma unroll
    for (int nt = 0; nt < 8; nt++) {
        int o = nt * 64 + wv * 16 + ln;            // [0, 512)
        int row = third * 512 + o;
        const unsigned short* bp = wbf + (size_t)row * CH + quad * 8;
        bf16x8 wf[16];
        #pragma unroll
        for (int k = 0; k < 16; k++) wf[k] = *(const bf16x8*)(bp + k * 32);
        float bi = bias[row];
        #pragma unroll
        for (int qt = 0; qt < 2; qt++) {
            f32x4 acc = {0.f, 0.f, 0.f, 0.f};
            #pragma unroll
            for (int k = 0; k < 16; k++) {
                bf16x8 a = *(const bf16x8*)(&hn[qt * 16 + ln][quad * 8 + k * 32]);
                acc = __builtin_amdgcn_mfma_f32_16x16x32_bf16(a, wf[k], acc, 0, 0, 0);
            }
            int m = m0 + qt * 16 + quad * 4;
            if (third == 0) {
                #pragma unroll
                for (int r = 0; r < 4; r++)
                    Q[((size_t)b * NPIX + m + r) * CH + o] = f2b((acc[r] + bi) * scale);
            } else if (third == 1) {
                #pragma unroll
                for (int r = 0; r < 4; r++)
                    K[((size_t)b * NPIX + m + r) * CH + o] = f2b(acc[r] + bi);
            } else {
                bf16x4 pk;
                #pragma unroll
                for (int r = 0; r < 4; r++) pk[r] = f2b(acc[r] + bi);
                *(bf16x4*)(V + ((size_t)b * CH + o) * NPIX + m) = pk;
            }
        }
    }
}

// ---------------------------------------------------------------- attention (split-K flash)
// 1024 blocks of 256 threads, 2 blocks/CU (two independent barrier domains).
// bid&7 = XCD -> (batch, split): per-XCD K+V working set = 2MB (fits 4MB L2).
// Block: 32 queries x 1024 keys, 32-key LDS-double-buffered tiles.
__global__ __launch_bounds__(256, 2) void attn_kernel(
    const unsigned short* __restrict__ Qg,   // [b][n][c] bf16, pre-scaled
    const unsigned short* __restrict__ Kg,
    const unsigned short* __restrict__ Vg,
    unsigned short* __restrict__ Opart,      // [b][sp][n][c] bf16 numerators
    float* __restrict__ ml)                  // [b][sp][n][2] f32
{
    // LDS (73088 B -> 2 blocks/CU):
    //   [0,     32768) K buf0 [32 rows][64 chunks 16B], chunk c holds global chunk c^(row&7)
    //   [32768, 65536) K buf1
    //   [65536, 70144) Sbuf [32][36] f32
    //   [70144, 72704) Pbuf [32][40] bf16
    __shared__ __align__(16) char sm[72704];
    char* const Kb0 = sm;
    char* const Kb1 = sm + 32768;
    float (*Sbuf)[36]          = (float(*)[36])(sm + 65536);
    unsigned short (*Pbuf)[40] = (unsigned short(*)[40])(sm + 70144);
    __shared__ float mbuf[32], lbuf[32], abuf[32];

    int bid = blockIdx.x;
    int xcd = bid & 7;
    int b   = xcd >> 2;
    int sp  = xcd & 3;
    int q0  = (bid >> 3) << 5;   // 128 query-tiles of 32
    int tid = threadIdx.x;
    int wv = tid >> 6, lane = tid & 63, ln = lane & 15, quad = lane >> 4;
    const unsigned short* K  = Kg + ((size_t)b * NPIX + (size_t)sp * SPK) * CH;
    const unsigned short* V  = Vg + (size_t)b * CH * NPIX + (size_t)sp * SPK;
    const unsigned short* Qp = Qg + ((size_t)b * NPIX + q0) * CH;

    if (tid < 32) { mbuf[tid] = -1e30f; lbuf[tid] = 0.f; }

    // ---- q fragments for this wave's S subtile: wave = (qs, ks)
    int qs = wv >> 1, ks = wv & 1;
    bf16x8 qf[16];
    #pragma unroll
    for (int kt = 0; kt < 16; kt++)
        qf[kt] = *(const bf16x8*)(Qp + (size_t)(qs * 16 + ln) * CH + quad * 8 + kt * 32);

    // ---- prologue: async-stage K tile 0 (rows wv*8+is; xor = row&7 = is)
    #pragma unroll
    for (int is = 0; is < 8; is++) {
        int row = wv * 8 + is;
        gll16(Kb0 + row * 1024, K + (size_t)row * CH + ((lane ^ is) << 3));
    }

    f32x4 O[2][8];   // [qt][ct]: queries qt*16+ln, channels c0+ct*16+quad*4+r
    #pragma unroll
    for (int qt = 0; qt < 2; qt++)
        #pragma unroll
        for (int ct = 0; ct < 8; ct++) O[qt][ct] = (f32x4){0.f, 0.f, 0.f, 0.f};
    int c0 = wv * 128;
    const int swz = ln & 7;

    // ---- flash loop over 32 key-tiles of 32
    for (int it = 0; it < 32; ++it) {
        int kb = it << 5;
        const char* bufC = (it & 1) ? Kb1 : Kb0;
        char* bufN       = (it & 1) ? Kb0 : Kb1;

        // (a) V register loads for this tile — stay in flight until PV
        const unsigned short* vp = V + (size_t)(c0 + ln) * NPIX + kb + quad * 8;
        bf16x8 vf[8];
        #pragma unroll
        for (int ct = 0; ct < 8; ct++)
            vf[ct] = *(const bf16x8*)(vp + (size_t)ct * 16 * NPIX);

        // (b) async-stage next K tile (last iter wraps: harmless dummy)
        {
            int nkb = (kb + KT) & (SPK - 1);
            #pragma unroll
            for (int is = 0; is < 8; is++) {
                int row = wv * 8 + is;
                gll16(bufN + row * 1024, K + (size_t)(nkb + row) * CH + ((lane ^ is) << 3));
            }
        }

        // (c) fences each iter: between consecutive fences exactly 16 newer VMEM
        //     ops (V 8 + stage_next 8), so vmcnt(16) ⟹ stage(cur) landed.
        asm volatile("s_waitcnt vmcnt(16)" ::: "memory");
        __builtin_amdgcn_s_barrier();

        // (d) S: 16q x 16k per wave, two accumulator chains
        const char* kbase = bufC + (size_t)(ks * 16 + ln) * 1024;
        f32x4 Sa = {0.f, 0.f, 0.f, 0.f}, Sb = {0.f, 0.f, 0.f, 0.f};
        __builtin_amdgcn_s_setprio(1);
        #pragma unroll
        for (int kt = 0; kt < 16; kt += 2) {
            bf16x8 k0 = *(const bf16x8*)(kbase + ((((kt    ) * 4 + quad) ^ swz) << 4));
            bf16x8 k1 = *(const bf16x8*)(kbase + ((((kt + 1) * 4 + quad) ^ swz) << 4));
            Sa = __builtin_amdgcn_mfma_f32_16x16x32_bf16(qf[kt],     k0, Sa, 0, 0, 0);
            Sb = __builtin_amdgcn_mfma_f32_16x16x32_bf16(qf[kt + 1], k1, Sb, 0, 0, 0);
        }
        __builtin_amdgcn_s_setprio(0);
        f32x4 S = Sa + Sb;
        #pragma unroll
        for (int r = 0; r < 4; r++)
            Sbuf[qs * 16 + quad * 4 + r][ks * 16 + ln] = S[r];

        asm volatile("s_waitcnt lgkmcnt(0)" ::: "memory");
        __builtin_amdgcn_s_barrier();

        // (f) online softmax: row r by 8 threads, 4 keys each
        {
            int r = tid >> 3, j = tid & 7;
            f32x4 sv = *(const f32x4*)(&Sbuf[r][j * 4]);
            float mx = fmaxf(fmaxf(sv[0], sv[1]), fmaxf(sv[2], sv[3]));
            #pragma unroll
            for (int off = 1; off < 8; off <<= 1) mx = fmaxf(mx, __shfl_xor(mx, off, 64));
            float mprev = mbuf[r];
            float mnew  = fmaxf(mprev, mx);
            float alpha = __expf(mprev - mnew);
            float e0 = __expf(sv[0] - mnew), e1 = __expf(sv[1] - mnew);
            float e2 = __expf(sv[2] - mnew), e3 = __expf(sv[3] - mnew);
            bf16x4 pk = { (short)f2b(e0), (short)f2b(e1), (short)f2b(e2), (short)f2b(e3) };
            *(bf16x4*)(&Pbuf[r][j * 4]) = pk;
            float sum = e0 + e1 + e2 + e3;
            #pragma unroll
            for (int off = 1; off < 8; off <<= 1) sum += __shfl_xor(sum, off, 64);
            if (j == 0) { mbuf[r] = mnew; lbuf[r] = lbuf[r] * alpha + sum; abuf[r] = alpha; }
        }
        asm volatile("s_waitcnt lgkmcnt(0)" ::: "memory");
        __builtin_amdgcn_s_barrier();

        // (h) PV: one P-fragment per qt covers all 32 keys; 8 MFMA per qt
        #pragma unroll
        for (int qt = 0; qt < 2; qt++) {
            float al = abuf[qt * 16 + ln];
            #pragma unroll
            for (int ct = 0; ct < 8; ct++) {
                #pragma unroll
                for (int r = 0; r < 4; r++) O[qt][ct][r] *= al;
            }
            bf16x8 pf = *(const bf16x8*)(&Pbuf[qt * 16 + ln][quad * 8]);
            __builtin_amdgcn_s_setprio(1);
            #pragma unroll
            for (int ct = 0; ct < 8; ct++)
                O[qt][ct] = __builtin_amdgcn_mfma_f32_16x16x32_bf16(vf[ct], pf, O[qt][ct], 0, 0, 0);
            __builtin_amdgcn_s_setprio(0);
        }
    }
    asm volatile("s_waitcnt vmcnt(0)" ::: "memory");   // drain dummy stage before exit

    // ---- store partial O numerators (bf16) + m,l
    unsigned short* Ob = Opart + (((size_t)(b * NSP + sp) * NPIX + q0) * CH);
    #pragma unroll
    for (int qt = 0; qt < 2; qt++) {
        #pragma unroll
        for (int ct = 0; ct < 8; ct++) {
            bf16x4 pk;
            #pragma unroll
            for (int r = 0; r < 4; r++) pk[r] = f2b(O[qt][ct][r]);
            *(bf16x4*)(Ob + (size_t)(qt * 16 + ln) * CH + c0 + ct * 16 + quad * 4) = pk;
        }
    }
    if (tid < 32) {
        size_t i = ((size_t)(b * NSP + sp) * NPIX + q0 + tid) * 2;
        ml[i + 0] = mbuf[tid];
        ml[i + 1] = lbuf[tid];
    }
}

// ---------------------------------------------------------------- merge 4 splits + proj + residual
__global__ __launch_bounds__(512, 2) void merge_kernel(
    const float* __restrict__ x,
    const unsigned short* __restrict__ Opart,
    const float* __restrict__ ml,
    const unsigned short* __restrict__ pw,   // bf16 proj_w [512][512]
    const float* __restrict__ pb,
    float* __restrict__ out)
{
    __shared__ __align__(16) unsigned short ao[32][520];
    int b  = blockIdx.y;
    int q0 = blockIdx.x * 32;
    int tid = threadIdx.x;
    int wv = tid >> 6, lane = tid & 63, ln = lane & 15, quad = lane >> 4;

    {   // combine splits: p = tid&31 (pixel), cs = tid>>5 (16 slots of 8ch)
        int p = tid & 31, cs = tid >> 5;
        int n = q0 + p;
        float m[NSP], l[NSP];
        #pragma unroll
        for (int s = 0; s < NSP; s++) {
            size_t i = ((size_t)(b * NSP + s) * NPIX + n) * 2;
            m[s] = ml[i]; l[s] = ml[i + 1];
        }
        float M = fmaxf(fmaxf(m[0], m[1]), fmaxf(m[2], m[3]));
        float w[NSP]; float den = 0.f;
        #pragma unroll
        for (int s = 0; s < NSP; s++) { w[s] = __expf(m[s] - M); den += l[s] * w[s]; }
        float dinv = 1.f / den;
        #pragma unroll
        for (int s = 0; s < NSP; s++) w[s] *= dinv;
        #pragma unroll
        for (int k = 0; k < 4; k++) {
            int c = cs * 8 + k * 128;
            float acc8[8] = {0.f,0.f,0.f,0.f,0.f,0.f,0.f,0.f};
            #pragma unroll
            for (int s = 0; s < NSP; s++) {
                const unsigned short* Os = Opart + ((size_t)(b * NSP + s) * NPIX + n) * CH;
                bf16x8 a = *(const bf16x8*)(Os + c);
                #pragma unroll
                for (int j = 0; j < 8; j++) acc8[j] += b2f((unsigned short)a[j]) * w[s];
            }
            #pragma unroll
            for (int j = 0; j < 8; j++) ao[p][c + j] = f2b(acc8[j]);
        }
    }
    __syncthreads();

    // ---- proj: out channels [wv*64,+64) + bias + residual (fp32)
    #pragma unroll
    for (int nt = 0; nt < 4; nt++) {
        int o = wv * 64 + nt * 16 + ln;
        const unsigned short* bp = pw + (size_t)o * CH + quad * 8;
        bf16x8 wf[16];
        #pragma unroll
        for (int k = 0; k < 16; k++) wf[k] = *(const bf16x8*)(bp + k * 32);
        float bi = pb[o];
        #pragma unroll
        for (int qt = 0; qt < 2; qt++) {
            f32x4 acc = {0.f, 0.f, 0.f, 0.f};
            #pragma unroll
            for (int k = 0; k < 16; k++) {
                bf16x8 a = *(const bf16x8*)(&ao[qt * 16 + ln][quad * 8 + k * 32]);
                acc = __builtin_amdgcn_mfma_f32_16x16x32_bf16(a, wf[k], acc, 0, 0, 0);
            }
            size_t base = ((size_t)b * CH + o) * NPIX + q0 + qt * 16 + quad * 4;
            f32x4 xin = *(const f32x4*)(x + base);
            f32x4 o4;
            #pragma unroll
            for (int r = 0; r < 4; r++) o4[r] = xin[r] + acc[r] + bi;
            *(f32x4*)(out + base) = o4;
        }
    }
}

// ----------------------------------------------------------------
extern "C" void kernel_launch(void* const* d_in, const int* in_sizes, int n_in,
                              void* d_out, int out_size, void* d_ws, size_t ws_size,
                              hipStream_t stream)
{
    const float* x      = (const float*)d_in[0];
    const float* gn_g   = (const float*)d_in[1];
    const float* gn_b   = (const float*)d_in[2];
    const float* qkv_w  = (const float*)d_in[3];
    const float* qkv_b  = (const float*)d_in[4];
    const float* proj_w = (const float*)d_in[5];
    const float* proj_b = (const float*)d_in[6];
    float* out = (float*)d_out;

    // Workspace (shorts): K 4M | V 4M | Q 4M | wbf 1M | stats | ml 128K | Opart 16M  (~58.3 MB)
    unsigned short* ws  = (unsigned short*)d_ws;
    unsigned short* Kb  = ws;                           // [2][4096][512] bf16
    unsigned short* Vb  = ws + 4u * 1024 * 1024;        // [2][512][4096] bf16
    unsigned short* Qb  = ws + 8u * 1024 * 1024;        // [2][4096][512] bf16 (scaled)
    unsigned short* wbf = ws + 12u * 1024 * 1024;       // qkv_w | proj_w, bf16
    unsigned short* wp  = wbf + 786432;
    float* stats = (float*)(ws + 13u * 1024 * 1024);              // 512 B
    float* ml    = (float*)(ws + 13u * 1024 * 1024 + 2048);       // [2][4][4096][2] f32
    unsigned short* Opart = ws + 13u * 1024 * 1024 + 2048 + 131072; // [2][4][4096][512] bf16

    convert_kernel<<<dim3(1048576 / 256), 256, 0, stream>>>(qkv_w, proj_w, wbf);
    stats_kernel  <<<dim3(64), 256, 0, stream>>>(x, stats);
    qkv_kernel    <<<dim3(NPIX / 32, BATCH, 3), 256, 0, stream>>>(
        x, wbf, qkv_b, gn_g, gn_b, stats, Qb, Kb, Vb);
    attn_kernel   <<<dim3(1024), 256, 0, stream>>>(Qb, Kb, Vb, Opart, ml);
    merge_kernel  <<<dim3(NPIX / 32, BATCH), 512, 0, stream>>>(
        x, Opart, ml, wp, proj_b, out);
}

// Round 4
// 447.042 us; speedup vs baseline: 1.0182x; 1.0182x over previous
//
#include <hip/hip_runtime.h>

typedef __attribute__((ext_vector_type(8))) short bf16x8;
typedef __attribute__((ext_vector_type(4))) short bf16x4;
typedef __attribute__((ext_vector_type(4))) float f32x4;
typedef __attribute__((ext_vector_type(2))) float f32x2;

#define BATCH 2
#define CH    512
#define NPIX  4096
#define NSP   4
#define SPK   1024   // keys per split
#define KT    32     // keys per tile

__device__ __forceinline__ unsigned short f2b(float f) {
    unsigned int u; __builtin_memcpy(&u, &f, 4);
    u = u + 0x7FFFu + ((u >> 16) & 1u);   // RNE
    return (unsigned short)(u >> 16);
}
__device__ __forceinline__ float b2f(unsigned short h) {
    unsigned int u = ((unsigned int)h) << 16;
    float f; __builtin_memcpy(&f, &u, 4);
    return f;
}
// async 16B/lane global->LDS (wave-uniform LDS base, per-lane global src)
__device__ __forceinline__ void gll16(void* lds, const void* g) {
    __builtin_amdgcn_global_load_lds(
        (const __attribute__((address_space(1))) void*)g,
        (__attribute__((address_space(3))) void*)lds, 16, 0, 0);
}

// ---------------------------------------------------------------- fp32 -> bf16 weight convert
__global__ __launch_bounds__(256) void convert_kernel(
    const float* __restrict__ qkv_w, const float* __restrict__ proj_w,
    unsigned short* __restrict__ wbf)
{
    int i = blockIdx.x * 256 + threadIdx.x;            // grid covers 1048576
    float v = (i < 786432) ? qkv_w[i] : proj_w[i - 786432];
    wbf[i] = f2b(v);
}

// ---------------------------------------------------------------- GN stats (2-stage, parallel)
__global__ __launch_bounds__(256) void stats1_kernel(
    const float* __restrict__ x, f32x2* __restrict__ part)
{
    int id = blockIdx.x;            // 256 blocks: bg*4 + quarter
    int bg = id >> 2, q = id & 3;
    int b = bg >> 5, g = bg & 31;
    const float* xp = x + ((size_t)b * CH + (size_t)g * 16 + q * 4) * NPIX;
    float s = 0.f, ss = 0.f;
    for (int i = threadIdx.x; i < 4 * NPIX; i += 256) {
        float v = xp[i]; s += v; ss += v * v;
    }
    for (int off = 32; off; off >>= 1) {
        s  += __shfl_down(s,  off, 64);
        ss += __shfl_down(ss, off, 64);
    }
    __shared__ float red[2][4];
    int wv = threadIdx.x >> 6;
    if ((threadIdx.x & 63) == 0) { red[0][wv] = s; red[1][wv] = ss; }
    __syncthreads();
    if (threadIdx.x == 0) {
        s  = red[0][0] + red[0][1] + red[0][2] + red[0][3];
        ss = red[1][0] + red[1][1] + red[1][2] + red[1][3];
        part[id] = (f32x2){s, ss};
    }
}

__global__ __launch_bounds__(64) void stats2_kernel(
    const f32x2* __restrict__ part, float* __restrict__ stats)
{
    int t = threadIdx.x;            // 64 = b*32+g
    float s = 0.f, ss = 0.f;
    #pragma unroll
    for (int q = 0; q < 4; q++) { f32x2 p = part[t * 4 + q]; s += p[0]; ss += p[1]; }
    const float inv = 1.f / (16 * NPIX);
    float mean = s * inv;
    float var  = ss * inv - mean * mean;
    stats[t * 2 + 0] = mean;
    stats[t * 2 + 1] = rsqrtf(var + 1e-6f);
}

// ---------------------------------------------------------------- GroupNorm materialize (bf16)
__global__ __launch_bounds__(256) void hn_kernel(
    const float* __restrict__ x,
    const float* __restrict__ gamma, const float* __restrict__ beta,
    const float* __restrict__ stats,
    unsigned short* __restrict__ hnb)    // [b][c][n] bf16
{
    size_t i = ((size_t)blockIdx.x * 256 + threadIdx.x) * 8;   // grid 2048
    int b = (int)(i >> 21), c = (int)((i >> 12) & 511);
    float mean = stats[(b * 32 + (c >> 4)) * 2 + 0];
    float rstd = stats[(b * 32 + (c >> 4)) * 2 + 1];
    float ga = gamma[c] * rstd;
    float be = beta[c] - mean * ga;
    f32x4 v0 = *(const f32x4*)(x + i);
    f32x4 v1 = *(const f32x4*)(x + i + 4);
    bf16x8 o;
    o[0] = f2b(v0[0]*ga+be); o[1] = f2b(v0[1]*ga+be);
    o[2] = f2b(v0[2]*ga+be); o[3] = f2b(v0[3]*ga+be);
    o[4] = f2b(v1[0]*ga+be); o[5] = f2b(v1[1]*ga+be);
    o[6] = f2b(v1[2]*ga+be); o[7] = f2b(v1[3]*ga+be);
    *(bf16x8*)(hnb + i) = o;
}

// ---------------------------------------------------------------- Q/K/V GEMM (64-pixel tiles)
// grid (64, 2, 3) = 384 blocks, 2 blocks/CU. third 0->Q (scaled), 1->K, 2->V.
__global__ __launch_bounds__(256, 2) void qkv_kernel(
    const unsigned short* __restrict__ hnb,  // [b][c][n] bf16
    const unsigned short* __restrict__ wbf,  // bf16 qkv_w [1536][512]
    const float* __restrict__ bias,
    unsigned short* __restrict__ Q,          // [b][n][c] pre-scaled
    unsigned short* __restrict__ K,          // [b][n][c]
    unsigned short* __restrict__ V)          // [b][c][n]
{
    __shared__ unsigned short hn[64][520];
    int b     = blockIdx.y;
    int third = blockIdx.z;
    int m0    = blockIdx.x * 64;
    int tid = threadIdx.x;
    {   // stage hn: p = tid&63 (pixel), cg = tid>>6 (4 channel slots)
        const unsigned short* hb = hnb + (size_t)b * CH * NPIX + m0;
        int p = tid & 63, cg = tid >> 6;
        for (int c0 = 0; c0 < CH; c0 += 4) {
            int c = c0 + cg;
            hn[p][c] = hb[(size_t)c * NPIX + p];
        }
    }
    __syncthreads();

    int wv = tid >> 6, lane = tid & 63, ln = lane & 15, quad = lane >> 4;
    const float scale = 0.04419417382415922f;  // 512^-0.5
    #pragma unroll
    for (int nt = 0; nt < 8; nt++) {
        int o = nt * 64 + wv * 16 + ln;            // [0, 512)
        int row = third * 512 + o;
        const unsigned short* bp = wbf + (size_t)row * CH + quad * 8;
        bf16x8 wf[16];
        #pragma unroll
        for (int k = 0; k < 16; k++) wf[k] = *(const bf16x8*)(bp + k * 32);
        float bi = bias[row];
        #pragma unroll
        for (int qt = 0; qt < 4; qt++) {
            f32x4 acc = {0.f, 0.f, 0.f, 0.f};
            #pragma unroll
            for (int k = 0; k < 16; k++) {
                bf16x8 a = *(const bf16x8*)(&hn[qt * 16 + ln][quad * 8 + k * 32]);
                acc = __builtin_amdgcn_mfma_f32_16x16x32_bf16(a, wf[k], acc, 0, 0, 0);
            }
            int m = m0 + qt * 16 + quad * 4;
            if (third == 0) {
                #pragma unroll
                for (int r = 0; r < 4; r++)
                    Q[((size_t)b * NPIX + m + r) * CH + o] = f2b((acc[r] + bi) * scale);
            } else if (third == 1) {
                #pragma unroll
                for (int r = 0; r < 4; r++)
                    K[((size_t)b * NPIX + m + r) * CH + o] = f2b(acc[r] + bi);
            } else {
                bf16x4 pk;
                #pragma unroll
                for (int r = 0; r < 4; r++) pk[r] = f2b(acc[r] + bi);
                *(bf16x4*)(V + ((size_t)b * CH + o) * NPIX + m) = pk;
            }
        }
    }
}

// ---------------------------------------------------------------- attention: in-register flash
// 512 blocks x 512 thr. bid&7 = XCD -> (b,sp): per-XCD K+V = 2MB (fits L2).
// Swapped QK^T: S = mfma(K,Q) => lane holds 8 S-values of ONE query (ln).
// Softmax fully in registers (2+2 shfl_xor); PV key order permuted (pi) so the
// P fragment is a local pack and V fragment is two contiguous b64 LDS reads.
// One barrier + one vmcnt(0) per iteration, after PV (stage has full iter in flight).
__global__ __launch_bounds__(512, 2) void attn_kernel(
    const unsigned short* __restrict__ Qg,   // [b][n][c] bf16, pre-scaled
    const unsigned short* __restrict__ Kg,   // [b][n][c]
    const unsigned short* __restrict__ Vg,   // [b][c][n]
    unsigned short* __restrict__ Opart,      // [b][sp][n][c] bf16 numerators
    float* __restrict__ ml)                  // [b][sp][n][2] f32
{
    // LDS: K dbuf 2x32KB @0 ([32 key-rows][64 chunks16B], chunk p holds global chunk p^(row&7));
    //      V dbuf 2x32KB @65536 ([512 ch-rows][4 chunks16B], chunk p holds global chunk p^(ch&3))
    __shared__ __align__(16) char sm[131072];

    int bid = blockIdx.x;
    int xcd = bid & 7;
    int b = xcd >> 2, sp = xcd & 3;
    int q0 = (bid >> 3) << 6;                // 64 query-tiles of 64
    int tid = threadIdx.x;
    int wv = tid >> 6, lane = tid & 63, ln = lane & 15, quad = lane >> 4;
    int qg = wv >> 1, cs = wv & 1;           // query group (16q), channel half (256c)

    const unsigned short* K = Kg + ((size_t)b * NPIX + (size_t)sp * SPK) * CH;
    const unsigned short* V = Vg + (size_t)b * CH * NPIX + (size_t)sp * SPK;
    const unsigned short* Qp = Qg + ((size_t)(b * NPIX + q0 + qg * 16)) * CH;

    char* const KB0 = sm;
    char* const KB1 = sm + 32768;
    char* const VB0 = sm + 65536;
    char* const VB1 = sm + 98304;

    // ---- stage helpers: K rows r=wv*4+j; V ch-rows 16 per gll16
    auto stageK = [&](char* buf, int kb) {
        #pragma unroll
        for (int j = 0; j < 4; j++) {
            int r = wv * 4 + j;
            gll16(buf + r * 1024,
                  K + (size_t)(kb + r) * CH + ((lane ^ (r & 7)) << 3));
        }
    };
    auto stageV = [&](char* buf, int kb) {
        #pragma unroll
        for (int j = 0; j < 4; j++) {
            int ch0 = wv * 64 + j * 16;
            int ch  = ch0 + (lane >> 2);
            gll16(buf + ch0 * 64,
                  V + (size_t)ch * NPIX + kb + (((lane & 3) ^ (ch & 3)) << 3));
        }
    };

    // ---- prologue: stage tile 0, load persistent Q fragments
    stageK(KB0, 0);
    stageV(VB0, 0);
    bf16x8 qf[16];
    #pragma unroll
    for (int kt = 0; kt < 16; kt++)
        qf[kt] = *(const bf16x8*)(Qp + (size_t)ln * CH + kt * 32 + quad * 8);
    asm volatile("s_waitcnt vmcnt(16)" ::: "memory");   // drains the 8 stage ops
    __builtin_amdgcn_s_barrier();

    // ---- per-lane LDS read bases (swizzle folded: addr = base ^ const + imm)
    const int BK = ln * 1024 + ((quad ^ (ln & 3)) << 4) + (((ln >> 2) & 1) << 6);
    const int BV = cs * 16384 + ln * 64 + (((quad >> 1) ^ (ln & 3)) << 4) + ((quad & 1) << 3);

    f32x4 O[16];
    #pragma unroll
    for (int i = 0; i < 16; i++) O[i] = (f32x4){0.f, 0.f, 0.f, 0.f};
    float m_reg = -1e30f, l_reg = 0.f;

    for (int it = 0; it < SPK / KT; ++it) {
        char* const KBc = (it & 1) ? KB1 : KB0;
        char* const VBc = (it & 1) ? VB1 : VB0;
        char* const KBn = (it & 1) ? KB0 : KB1;
        char* const VBn = (it & 1) ? VB0 : VB1;
        int nkb = ((it + 1) * KT) & (SPK - 1);   // last iter wraps: harmless dummy

        stageK(KBn, nkb);
        stageV(VBn, nkb);

        // ---- S = mfma(K, Q): two 16-key halves; lane -> query ln, keys H*16+quad*4+r
        const char* kE = KBc + BK;
        const char* kO = KBc + (BK ^ 64);
        f32x4 Sa = {0.f,0.f,0.f,0.f}, Sb = {0.f,0.f,0.f,0.f};
        __builtin_amdgcn_s_setprio(1);
        #pragma unroll
        for (int kt = 0; kt < 16; kt++) {
            const char* p = (kt & 1) ? kO : kE;
            bf16x8 k0 = *(const bf16x8*)(p + (kt >> 1) * 128);
            bf16x8 k1 = *(const bf16x8*)(p + (kt >> 1) * 128 + 16384);
            Sa = __builtin_amdgcn_mfma_f32_16x16x32_bf16(k0, qf[kt], Sa, 0, 0, 0);
            Sb = __builtin_amdgcn_mfma_f32_16x16x32_bf16(k1, qf[kt], Sb, 0, 0, 0);
        }
        __builtin_amdgcn_s_setprio(0);

        // ---- in-register online softmax (query = ln; quads replicate)
        float mx = fmaxf(fmaxf(fmaxf(Sa[0],Sa[1]), fmaxf(Sa[2],Sa[3])),
                         fmaxf(fmaxf(Sb[0],Sb[1]), fmaxf(Sb[2],Sb[3])));
        mx = fmaxf(mx, __shfl_xor(mx, 16, 64));
        mx = fmaxf(mx, __shfl_xor(mx, 32, 64));
        float mold = m_reg;
        float mnew = fmaxf(mold, mx);
        int resc = __any(mnew > mold);
        float alpha = __expf(mold - mnew);
        float e0 = __expf(Sa[0]-mnew), e1 = __expf(Sa[1]-mnew);
        float e2 = __expf(Sa[2]-mnew), e3 = __expf(Sa[3]-mnew);
        float e4 = __expf(Sb[0]-mnew), e5 = __expf(Sb[1]-mnew);
        float e6 = __expf(Sb[2]-mnew), e7 = __expf(Sb[3]-mnew);
        float ts = ((e0+e1)+(e2+e3)) + ((e4+e5)+(e6+e7));
        ts += __shfl_xor(ts, 16, 64);
        ts += __shfl_xor(ts, 32, 64);
        l_reg = l_reg * alpha + ts;
        m_reg = mnew;
        bf16x8 pf;
        pf[0] = f2b(e0); pf[1] = f2b(e1); pf[2] = f2b(e2); pf[3] = f2b(e3);
        pf[4] = f2b(e4); pf[5] = f2b(e5); pf[6] = f2b(e6); pf[7] = f2b(e7);
        if (resc) {
            #pragma unroll
            for (int ct = 0; ct < 16; ct++) {
                #pragma unroll
                for (int r = 0; r < 4; r++) O[ct][r] *= alpha;
            }
        }

        // ---- PV: A = V (channels x pi-permuted keys), B = pf (local pack)
        const char* vLo = VBc + BV;
        const char* vHi = VBc + (BV ^ 32);
        __builtin_amdgcn_s_setprio(1);
        #pragma unroll
        for (int ct = 0; ct < 16; ct++) {
            bf16x4 lo = *(const bf16x4*)(vLo + ct * 1024);
            bf16x4 hi = *(const bf16x4*)(vHi + ct * 1024);
            bf16x8 vv = __builtin_shufflevector(lo, hi, 0, 1, 2, 3, 4, 5, 6, 7);
            O[ct] = __builtin_amdgcn_mfma_f32_16x16x32_bf16(vv, pf, O[ct], 0, 0, 0);
        }
        __builtin_amdgcn_s_setprio(0);

        // stage(next) drained here (had the whole iteration in flight), then sync
        asm volatile("s_waitcnt vmcnt(0)" ::: "memory");
        __builtin_amdgcn_s_barrier();
    }

    // ---- store partial O numerators + m,l
    size_t n = (size_t)(b * NSP + sp) * NPIX + q0 + qg * 16 + ln;
    unsigned short* Ob = Opart + n * CH + cs * 256 + quad * 4;
    #pragma unroll
    for (int ct = 0; ct < 16; ct++) {
        bf16x4 pk;
        #pragma unroll
        for (int r = 0; r < 4; r++) pk[r] = f2b(O[ct][r]);
        *(bf16x4*)(Ob + ct * 16) = pk;
    }
    if (cs == 0 && quad == 0) {
        ml[n * 2 + 0] = m_reg;
        ml[n * 2 + 1] = l_reg;
    }
}

// ---------------------------------------------------------------- merge 4 splits + proj + residual
__global__ __launch_bounds__(512, 2) void merge_kernel(
    const float* __restrict__ x,
    const unsigned short* __restrict__ Opart,
    const float* __restrict__ ml,
    const unsigned short* __restrict__ pw,   // bf16 proj_w [512][512]
    const float* __restrict__ pb,
    float* __restrict__ out)
{
    __shared__ __align__(16) unsigned short ao[32][520];
    int b  = blockIdx.y;
    int q0 = blockIdx.x * 32;
    int tid = threadIdx.x;
    int wv = tid >> 6, lane = tid & 63, ln = lane & 15, quad = lane >> 4;

    {   // combine splits: p = tid&31 (pixel), cs = tid>>5 (16 slots of 8ch)
        int p = tid & 31, cs = tid >> 5;
        int n = q0 + p;
        float m[NSP], l[NSP];
        #pragma unroll
        for (int s = 0; s < NSP; s++) {
            size_t i = ((size_t)(b * NSP + s) * NPIX + n) * 2;
            m[s] = ml[i]; l[s] = ml[i + 1];
        }
        float M = fmaxf(fmaxf(m[0], m[1]), fmaxf(m[2], m[3]));
        float w[NSP]; float den = 0.f;
        #pragma unroll
        for (int s = 0; s < NSP; s++) { w[s] = __expf(m[s] - M); den += l[s] * w[s]; }
        float dinv = 1.f / den;
        #pragma unroll
        for (int s = 0; s < NSP; s++) w[s] *= dinv;
        #pragma unroll
        for (int k = 0; k < 4; k++) {
            int c = cs * 8 + k * 128;
            float acc8[8] = {0.f,0.f,0.f,0.f,0.f,0.f,0.f,0.f};
            #pragma unroll
            for (int s = 0; s < NSP; s++) {
                const unsigned short* Os = Opart + ((size_t)(b * NSP + s) * NPIX + n) * CH;
                bf16x8 a = *(const bf16x8*)(Os + c);
                #pragma unroll
                for (int j = 0; j < 8; j++) acc8[j] += b2f((unsigned short)a[j]) * w[s];
            }
            #pragma unroll
            for (int j = 0; j < 8; j++) ao[p][c + j] = f2b(acc8[j]);
        }
    }
    __syncthreads();

    // ---- proj: out channels [wv*64,+64) + bias + residual (fp32)
    #pragma unroll
    for (int nt = 0; nt < 4; nt++) {
        int o = wv * 64 + nt * 16 + ln;
        const unsigned short* bp = pw + (size_t)o * CH + quad * 8;
        bf16x8 wf[16];
        #pragma unroll
        for (int k = 0; k < 16; k++) wf[k] = *(const bf16x8*)(bp + k * 32);
        float bi = pb[o];
        #pragma unroll
        for (int qt = 0; qt < 2; qt++) {
            f32x4 acc = {0.f, 0.f, 0.f, 0.f};
            #pragma unroll
            for (int k = 0; k < 16; k++) {
                bf16x8 a = *(const bf16x8*)(&ao[qt * 16 + ln][quad * 8 + k * 32]);
                acc = __builtin_amdgcn_mfma_f32_16x16x32_bf16(a, wf[k], acc, 0, 0, 0);
            }
            size_t base = ((size_t)b * CH + o) * NPIX + q0 + qt * 16 + quad * 4;
            f32x4 xin = *(const f32x4*)(x + base);
            f32x4 o4;
            #pragma unroll
            for (int r = 0; r < 4; r++) o4[r] = xin[r] + acc[r] + bi;
            *(f32x4*)(out + base) = o4;
        }
    }
}

// ----------------------------------------------------------------
extern "C" void kernel_launch(void* const* d_in, const int* in_sizes, int n_in,
                              void* d_out, int out_size, void* d_ws, size_t ws_size,
                              hipStream_t stream)
{
    const float* x      = (const float*)d_in[0];
    const float* gn_g   = (const float*)d_in[1];
    const float* gn_b   = (const float*)d_in[2];
    const float* qkv_w  = (const float*)d_in[3];
    const float* qkv_b  = (const float*)d_in[4];
    const float* proj_w = (const float*)d_in[5];
    const float* proj_b = (const float*)d_in[6];
    float* out = (float*)d_out;

    // Workspace (shorts): K 4M | V 4M | Q 4M | wbf 1M | stats/part/ml | Opart 16M (~58.3MB)
    // hnb (4M shorts) aliases the START of Opart: written by hn_kernel, read by qkv,
    // then clobbered by attn's Opart writes (qkv complete by then; stream-serialized).
    unsigned short* ws  = (unsigned short*)d_ws;
    unsigned short* Kb  = ws;                           // [2][4096][512]
    unsigned short* Vb  = ws + 4u * 1024 * 1024;        // [2][512][4096]
    unsigned short* Qb  = ws + 8u * 1024 * 1024;        // [2][4096][512] (scaled)
    unsigned short* wbf = ws + 12u * 1024 * 1024;       // qkv_w | proj_w bf16
    unsigned short* wp  = wbf + 786432;
    float* stats = (float*)(ws + 13u * 1024 * 1024);             // 128 f32
    f32x2* part  = (f32x2*)(ws + 13u * 1024 * 1024 + 1024);      // 256 f32x2
    float* ml    = (float*)(ws + 13u * 1024 * 1024 + 4096);      // [2][4][4096][2] f32
    unsigned short* Opart = ws + 13u * 1024 * 1024 + 4096 + 131072;
    unsigned short* hnb   = Opart;                      // alias (see above)

    convert_kernel<<<dim3(1048576 / 256), 256, 0, stream>>>(qkv_w, proj_w, wbf);
    stats1_kernel <<<dim3(256), 256, 0, stream>>>(x, part);
    stats2_kernel <<<dim3(1), 64, 0, stream>>>(part, stats);
    hn_kernel     <<<dim3(2048), 256, 0, stream>>>(x, gn_g, gn_b, stats, hnb);
    qkv_kernel    <<<dim3(NPIX / 64, BATCH, 3), 256, 0, stream>>>(
        hnb, wbf, qkv_b, Qb, Kb, Vb);
    attn_kernel   <<<dim3(512), 512, 0, stream>>>(Qb, Kb, Vb, Opart, ml);
    merge_kernel  <<<dim3(NPIX / 32, BATCH), 512, 0, stream>>>(
        x, Opart, ml, wp, proj_b, out);
}